// Round 5
// baseline (187.777 us; speedup 1.0000x reference)
//
#include <hip/hip_runtime.h>
#include <hip/hip_bf16.h>
#include <math.h>

#define NEXP 64
#define TOPK 8
#define RPB 256                 // rows per block (= block size, thread-per-row)

__global__ __launch_bounds__(256, 4) void topk_router_kernel(
    const float* __restrict__ logits,
    float* __restrict__ w_out,      // [N,8] weights
    float* __restrict__ id_out,     // [N,8] ids stored as float values
    float* __restrict__ l_out,      // [N,64] passthrough copy
    int nrows)
{
    // Half-row tile reused across two phases: tile[c][r ^ c], c in 0..7.
    // XOR swizzle -> 8 lanes per 4-bank group on both write and read side
    // (= ds_*_b128 hardware minimum; measured 0 conflicts in prior rounds).
    __shared__ float4 tile[8 * RPB];   // 32 KB

    const int t = threadIdx.x;
    const size_t blockBase4 = (size_t)blockIdx.x * (RPB * 16);
    const size_t totalChunks = (size_t)nrows * 16;

    const float4* __restrict__ src = (const float4*)logits;
    float4* __restrict__ dst = (float4*)l_out;

    // ---- phase A stage: chunks 0..7 of all 256 rows (coalesced) ----
    #pragma unroll
    for (int i = 0; i < 8; ++i) {
        int j = i * 256 + t;
        int r = j >> 3, c = j & 7;
        size_t g = blockBase4 + (size_t)r * 16 + c;
        if (g < totalChunks) {
            float4 v = src[g];
            dst[g] = v;                         // passthrough copy
            tile[c * RPB + (r ^ c)] = v;
        }
    }

    // ---- issue phase-B global loads now (in flight across barrier+compute) ----
    float4 vb[8];
    #pragma unroll
    for (int i = 0; i < 8; ++i) {
        int j = i * 256 + t;
        int r = j >> 3, c = j & 7;
        size_t g = blockBase4 + (size_t)r * 16 + 8 + c;
        vb[i] = (g < totalChunks) ? src[g] : make_float4(0.f, 0.f, 0.f, 0.f);
    }

    // barrier 1: only LDS ordering is needed. Raw s_barrier + lgkmcnt(0)
    // avoids __syncthreads' s_waitcnt vmcnt(0) -- the 16 l_out stores and
    // 8 vb loads stay in flight instead of draining three times per block.
    asm volatile("s_waitcnt lgkmcnt(0)" ::: "memory");
    __builtin_amdgcn_s_barrier();
    asm volatile("" ::: "memory");

    const int row = blockIdx.x * RPB + t;
    const bool active = (row < nrows);

    // ---- read my row's chunks 0..7 ----
    float4 d0 = tile[0 * RPB + (t ^ 0)];
    float4 d1 = tile[1 * RPB + (t ^ 1)];
    float4 d2 = tile[2 * RPB + (t ^ 2)];
    float4 d3 = tile[3 * RPB + (t ^ 3)];
    float4 d4 = tile[4 * RPB + (t ^ 4)];
    float4 d5 = tile[5 * RPB + (t ^ 5)];
    float4 d6 = tile[6 * RPB + (t ^ 6)];
    float4 d7 = tile[7 * RPB + (t ^ 7)];

    // ---- top-8 by logit (stable: strict >, increasing index) + max of
    // rejected (rm) for the 8/9-boundary tie screen ----
    float tv0 = -INFINITY, tv1 = -INFINITY, tv2 = -INFINITY, tv3 = -INFINITY;
    float tv4 = -INFINITY, tv5 = -INFINITY, tv6 = -INFINITY, tv7 = -INFINITY;
    float rm  = -INFINITY;
    int   ti0 = 0, ti1 = 0, ti2 = 0, ti3 = 0;
    int   ti4 = 0, ti5 = 0, ti6 = 0, ti7 = 0;

#define INSERT_STAGE(TV, TI)                              \
    {                                                     \
        bool gt = (x > TV);                               \
        float nv = gt ? x  : TV;                          \
        float cv = gt ? TV : x;                           \
        int   ni = gt ? xi : TI;                          \
        int   ci = gt ? TI : xi;                          \
        TV = nv; x = cv; TI = ni; xi = ci;                \
    }

#define INSERT_ELEM(X, XI)                                \
    {                                                     \
        float x = (X); int xi = (XI);                     \
        INSERT_STAGE(tv0, ti0)                            \
        INSERT_STAGE(tv1, ti1)                            \
        INSERT_STAGE(tv2, ti2)                            \
        INSERT_STAGE(tv3, ti3)                            \
        INSERT_STAGE(tv4, ti4)                            \
        INSERT_STAGE(tv5, ti5)                            \
        INSERT_STAGE(tv6, ti6)                            \
        INSERT_STAGE(tv7, ti7)                            \
        rm = fmaxf(rm, x);                                \
    }

#define INSERT_CHUNK(D, CI)                               \
    INSERT_ELEM((D).x, (CI) * 4 + 0)                      \
    INSERT_ELEM((D).y, (CI) * 4 + 1)                      \
    INSERT_ELEM((D).z, (CI) * 4 + 2)                      \
    INSERT_ELEM((D).w, (CI) * 4 + 3)

    INSERT_CHUNK(d0, 0)
    INSERT_CHUNK(d1, 1)
    INSERT_CHUNK(d2, 2)
    INSERT_CHUNK(d3, 3)
    INSERT_CHUNK(d4, 4)
    INSERT_CHUNK(d5, 5)
    INSERT_CHUNK(d6, 6)
    INSERT_CHUNK(d7, 7)

    // barrier 2: my ds_reads are consumed (register deps already forced the
    // waits); safe to overwrite the tile after all lanes pass.
    asm volatile("s_waitcnt lgkmcnt(0)" ::: "memory");
    __builtin_amdgcn_s_barrier();
    asm volatile("" ::: "memory");

    // ---- phase B stage: chunks 8..15 into the same tile ----
    #pragma unroll
    for (int i = 0; i < 8; ++i) {
        int j = i * 256 + t;
        int r = j >> 3, c = j & 7;
        size_t g = blockBase4 + (size_t)r * 16 + 8 + c;
        if (g < totalChunks) dst[g] = vb[i];    // passthrough copy
        tile[c * RPB + (r ^ c)] = vb[i];
    }

    // barrier 3: LDS writes visible; again no vmcnt drain.
    asm volatile("s_waitcnt lgkmcnt(0)" ::: "memory");
    __builtin_amdgcn_s_barrier();
    asm volatile("" ::: "memory");

    d0 = tile[0 * RPB + (t ^ 0)];
    d1 = tile[1 * RPB + (t ^ 1)];
    d2 = tile[2 * RPB + (t ^ 2)];
    d3 = tile[3 * RPB + (t ^ 3)];
    d4 = tile[4 * RPB + (t ^ 4)];
    d5 = tile[5 * RPB + (t ^ 5)];
    d6 = tile[6 * RPB + (t ^ 6)];
    d7 = tile[7 * RPB + (t ^ 7)];

    INSERT_CHUNK(d0, 8)
    INSERT_CHUNK(d1, 9)
    INSERT_CHUNK(d2, 10)
    INSERT_CHUNK(d3, 11)
    INSERT_CHUNK(d4, 12)
    INSERT_CHUNK(d5, 13)
    INSERT_CHUNK(d6, 14)
    INSERT_CHUNK(d7, 15)

    if (!active) return;

    // ---- tie screen: fp32 softmax can only collapse logits whose gap is
    // < ~2 ulp of (l - max) <= ~9.6e-7 at |d|<8; screen at 1e-6 covers all
    // pairs that involve a selected element (7 in-top gaps + 8/9 boundary).
    const float T = 1e-6f;
    bool tie = ((tv0 - tv1) <= T) | ((tv1 - tv2) <= T) | ((tv2 - tv3) <= T) |
               ((tv3 - tv4) <= T) | ((tv4 - tv5) <= T) | ((tv5 - tv6) <= T) |
               ((tv6 - tv7) <= T) | ((tv7 - rm)  <= T);

    float ce0, ce1, ce2, ce3, ce4, ce5, ce6, ce7;
    int   o0, o1, o2, o3, o4, o5, o6, o7;

    if (__builtin_expect(!tie, 1)) {
        // fast path: no representable score tie possible
        ce0 = 1.0f;
        ce1 = __expf(tv1 - tv0); ce2 = __expf(tv2 - tv0);
        ce3 = __expf(tv3 - tv0); ce4 = __expf(tv4 - tv0);
        ce5 = __expf(tv5 - tv0); ce6 = __expf(tv6 - tv0);
        ce7 = __expf(tv7 - tv0);
        o0 = ti0; o1 = ti1; o2 = ti2; o3 = ti3;
        o4 = ti4; o5 = ti5; o6 = ti6; o7 = ti7;
    } else {
        // exact path (rare, exec-masked): re-read the row from global and
        // redo depth-10 selection + correctly-rounded-exp tie semantics.
        const float* rowp = logits + (size_t)row * NEXP;
        float sv0 = -INFINITY, sv1 = -INFINITY, sv2 = -INFINITY, sv3 = -INFINITY;
        float sv4 = -INFINITY, sv5 = -INFINITY, sv6 = -INFINITY, sv7 = -INFINITY;
        float sv8 = -INFINITY, sv9 = -INFINITY;
        int   si0 = 0, si1 = 0, si2 = 0, si3 = 0, si4 = 0;
        int   si5 = 0, si6 = 0, si7 = 0, si8 = 0, si9 = 0;

#define SLOW_STAGE(TV, TI)                                \
    {                                                     \
        bool gt = (x > TV);                               \
        float nv = gt ? x  : TV;                          \
        float cv = gt ? TV : x;                           \
        int   ni = gt ? xi : TI;                          \
        int   ci = gt ? TI : xi;                          \
        TV = nv; x = cv; TI = ni; xi = ci;                \
    }

        #pragma unroll 1
        for (int e = 0; e < NEXP; ++e) {
            float x = rowp[e]; int xi = e;
            SLOW_STAGE(sv0, si0)
            SLOW_STAGE(sv1, si1)
            SLOW_STAGE(sv2, si2)
            SLOW_STAGE(sv3, si3)
            SLOW_STAGE(sv4, si4)
            SLOW_STAGE(sv5, si5)
            SLOW_STAGE(sv6, si6)
            SLOW_STAGE(sv7, si7)
            SLOW_STAGE(sv8, si8)
            SLOW_STAGE(sv9, si9)
        }

        double m = (double)sv0;
        float s0 = (float)exp((double)sv0 - m);
        float s1 = (float)exp((double)sv1 - m);
        float s2 = (float)exp((double)sv2 - m);
        float s3 = (float)exp((double)sv3 - m);
        float s4 = (float)exp((double)sv4 - m);
        float s5 = (float)exp((double)sv5 - m);
        float s6 = (float)exp((double)sv6 - m);
        float s7 = (float)exp((double)sv7 - m);
        float s8 = (float)exp((double)sv8 - m);
        float s9 = (float)exp((double)sv9 - m);

#define TIESWAP(CA, IA, CB, IB)                           \
    {                                                     \
        bool sw = (CA == CB) && (IA > IB);                \
        int tt = IA;                                      \
        IA = sw ? IB : IA;                                \
        IB = sw ? tt : IB;                                \
    }
#define TIEPASS                                           \
    TIESWAP(s0, si0, s1, si1)                             \
    TIESWAP(s1, si1, s2, si2)                             \
    TIESWAP(s2, si2, s3, si3)                             \
    TIESWAP(s3, si3, s4, si4)                             \
    TIESWAP(s4, si4, s5, si5)                             \
    TIESWAP(s5, si5, s6, si6)                             \
    TIESWAP(s6, si6, s7, si7)                             \
    TIESWAP(s7, si7, s8, si8)                             \
    TIESWAP(s8, si8, s9, si9)

        TIEPASS
        TIEPASS
        TIEPASS
        TIEPASS

        ce0 = s0; ce1 = s1; ce2 = s2; ce3 = s3;
        ce4 = s4; ce5 = s5; ce6 = s6; ce7 = s7;
        o0 = si0; o1 = si1; o2 = si2; o3 = si3;
        o4 = si4; o5 = si5; o6 = si6; o7 = si7;
    }

    float s = ((ce0 + ce1) + (ce2 + ce3)) + ((ce4 + ce5) + (ce6 + ce7));
    float r = 1.0f / s;

    float4 w0 = make_float4(ce0 * r, ce1 * r, ce2 * r, ce3 * r);
    float4 w1 = make_float4(ce4 * r, ce5 * r, ce6 * r, ce7 * r);
    float4 i0 = make_float4((float)o0, (float)o1, (float)o2, (float)o3);
    float4 i1 = make_float4((float)o4, (float)o5, (float)o6, (float)o7);

    float4* __restrict__ wp = (float4*)(w_out + (size_t)row * TOPK);
    wp[0] = w0; wp[1] = w1;
    float4* __restrict__ ip = (float4*)(id_out + (size_t)row * TOPK);
    ip[0] = i0; ip[1] = i1;
}

extern "C" void kernel_launch(void* const* d_in, const int* in_sizes, int n_in,
                              void* d_out, int out_size, void* d_ws, size_t ws_size,
                              hipStream_t stream) {
    const float* logits = (const float*)d_in[0];
    int nrows = in_sizes[0] / NEXP;

    float* out    = (float*)d_out;
    float* w_out  = out;
    float* id_out = out + (size_t)nrows * TOPK;
    float* l_out  = out + (size_t)nrows * 2 * TOPK;

    int threads = 256;
    int blocks = (nrows + RPB - 1) / RPB;
    topk_router_kernel<<<blocks, threads, 0, stream>>>(logits, w_out, id_out, l_out, nrows);
}

// Round 6
// 177.376 us; speedup vs baseline: 1.0586x; 1.0586x over previous
//
#include <hip/hip_runtime.h>
#include <hip/hip_bf16.h>
#include <math.h>

#define NEXP 64
#define TOPK 8
#define RPB 256                 // rows per block (= block size, thread-per-row)

__global__ __launch_bounds__(256) void topk_router_kernel(
    const float* __restrict__ logits,
    float* __restrict__ w_out,      // [N,8] weights
    float* __restrict__ id_out,     // [N,8] ids stored as float values
    float* __restrict__ l_out,      // [N,64] passthrough copy
    int nrows)
{
    // Half-row tile reused across two phases: tile[c][r ^ c], c in 0..7.
    // XOR swizzle -> 8 lanes per 4-bank group on both write and read side
    // (= ds_*_b128 hardware minimum; measured 0 conflicts in prior rounds).
    __shared__ float4 tile[8 * RPB];   // 32 KB -> 5 blocks/CU LDS limit

    const int t = threadIdx.x;
    const size_t blockBase4 = (size_t)blockIdx.x * (RPB * 16);
    const size_t totalChunks = (size_t)nrows * 16;

    const float4* __restrict__ src = (const float4*)logits;
    float4* __restrict__ dst = (float4*)l_out;

    // ---- phase A stage: chunks 0..7 of all 256 rows (coalesced) ----
    #pragma unroll
    for (int i = 0; i < 8; ++i) {
        int j = i * 256 + t;
        int r = j >> 3, c = j & 7;
        size_t g = blockBase4 + (size_t)r * 16 + c;
        if (g < totalChunks) {
            float4 v = src[g];
            dst[g] = v;                         // passthrough copy
            tile[c * RPB + (r ^ c)] = v;
        }
    }

    // ---- issue phase-B global loads now (in flight across barrier+compute) ----
    float4 vb[8];
    #pragma unroll
    for (int i = 0; i < 8; ++i) {
        int j = i * 256 + t;
        int r = j >> 3, c = j & 7;
        size_t g = blockBase4 + (size_t)r * 16 + 8 + c;
        vb[i] = (g < totalChunks) ? src[g] : make_float4(0.f, 0.f, 0.f, 0.f);
    }

    // barrier 1: only LDS ordering is needed. Raw s_barrier + lgkmcnt(0)
    // avoids __syncthreads' s_waitcnt vmcnt(0) -- the 16 l_out stores and
    // 8 vb loads stay in flight instead of draining three times per block.
    asm volatile("s_waitcnt lgkmcnt(0)" ::: "memory");
    __builtin_amdgcn_s_barrier();
    asm volatile("" ::: "memory");

    const int row = blockIdx.x * RPB + t;
    const bool active = (row < nrows);

    // ---- read my row's chunks 0..7 ----
    float4 d0 = tile[0 * RPB + (t ^ 0)];
    float4 d1 = tile[1 * RPB + (t ^ 1)];
    float4 d2 = tile[2 * RPB + (t ^ 2)];
    float4 d3 = tile[3 * RPB + (t ^ 3)];
    float4 d4 = tile[4 * RPB + (t ^ 4)];
    float4 d5 = tile[5 * RPB + (t ^ 5)];
    float4 d6 = tile[6 * RPB + (t ^ 6)];
    float4 d7 = tile[7 * RPB + (t ^ 7)];

    // ---- top-8 by logit (stable: strict >, increasing index) + max of
    // rejected (rm) for the 8/9-boundary tie screen ----
    float tv0 = -INFINITY, tv1 = -INFINITY, tv2 = -INFINITY, tv3 = -INFINITY;
    float tv4 = -INFINITY, tv5 = -INFINITY, tv6 = -INFINITY, tv7 = -INFINITY;
    float rm  = -INFINITY;
    int   ti0 = 0, ti1 = 0, ti2 = 0, ti3 = 0;
    int   ti4 = 0, ti5 = 0, ti6 = 0, ti7 = 0;

#define INSERT_STAGE(TV, TI)                              \
    {                                                     \
        bool gt = (x > TV);                               \
        float nv = gt ? x  : TV;                          \
        float cv = gt ? TV : x;                           \
        int   ni = gt ? xi : TI;                          \
        int   ci = gt ? TI : xi;                          \
        TV = nv; x = cv; TI = ni; xi = ci;                \
    }

#define INSERT_ELEM(X, XI)                                \
    {                                                     \
        float x = (X); int xi = (XI);                     \
        INSERT_STAGE(tv0, ti0)                            \
        INSERT_STAGE(tv1, ti1)                            \
        INSERT_STAGE(tv2, ti2)                            \
        INSERT_STAGE(tv3, ti3)                            \
        INSERT_STAGE(tv4, ti4)                            \
        INSERT_STAGE(tv5, ti5)                            \
        INSERT_STAGE(tv6, ti6)                            \
        INSERT_STAGE(tv7, ti7)                            \
        rm = fmaxf(rm, x);                                \
    }

#define INSERT_CHUNK(D, CI)                               \
    INSERT_ELEM((D).x, (CI) * 4 + 0)                      \
    INSERT_ELEM((D).y, (CI) * 4 + 1)                      \
    INSERT_ELEM((D).z, (CI) * 4 + 2)                      \
    INSERT_ELEM((D).w, (CI) * 4 + 3)

    INSERT_CHUNK(d0, 0)
    INSERT_CHUNK(d1, 1)
    INSERT_CHUNK(d2, 2)
    INSERT_CHUNK(d3, 3)
    INSERT_CHUNK(d4, 4)
    INSERT_CHUNK(d5, 5)
    INSERT_CHUNK(d6, 6)
    INSERT_CHUNK(d7, 7)

    // barrier 2: my ds_reads are consumed (register deps already forced the
    // waits); safe to overwrite the tile after all lanes pass.
    asm volatile("s_waitcnt lgkmcnt(0)" ::: "memory");
    __builtin_amdgcn_s_barrier();
    asm volatile("" ::: "memory");

    // ---- phase B stage: chunks 8..15 into the same tile ----
    #pragma unroll
    for (int i = 0; i < 8; ++i) {
        int j = i * 256 + t;
        int r = j >> 3, c = j & 7;
        size_t g = blockBase4 + (size_t)r * 16 + 8 + c;
        if (g < totalChunks) dst[g] = vb[i];    // passthrough copy
        tile[c * RPB + (r ^ c)] = vb[i];
    }

    // barrier 3: LDS writes visible; again no vmcnt drain.
    asm volatile("s_waitcnt lgkmcnt(0)" ::: "memory");
    __builtin_amdgcn_s_barrier();
    asm volatile("" ::: "memory");

    d0 = tile[0 * RPB + (t ^ 0)];
    d1 = tile[1 * RPB + (t ^ 1)];
    d2 = tile[2 * RPB + (t ^ 2)];
    d3 = tile[3 * RPB + (t ^ 3)];
    d4 = tile[4 * RPB + (t ^ 4)];
    d5 = tile[5 * RPB + (t ^ 5)];
    d6 = tile[6 * RPB + (t ^ 6)];
    d7 = tile[7 * RPB + (t ^ 7)];

    INSERT_CHUNK(d0, 8)
    INSERT_CHUNK(d1, 9)
    INSERT_CHUNK(d2, 10)
    INSERT_CHUNK(d3, 11)
    INSERT_CHUNK(d4, 12)
    INSERT_CHUNK(d5, 13)
    INSERT_CHUNK(d6, 14)
    INSERT_CHUNK(d7, 15)

    if (!active) return;

    // ---- tie screen: fp32 softmax can only collapse logits whose gap is
    // < ~2 ulp of (l - max) <= ~9.6e-7 at |d|<8; screen at 1e-6 covers all
    // pairs that involve a selected element (7 in-top gaps + 8/9 boundary).
    const float T = 1e-6f;
    bool tie = ((tv0 - tv1) <= T) | ((tv1 - tv2) <= T) | ((tv2 - tv3) <= T) |
               ((tv3 - tv4) <= T) | ((tv4 - tv5) <= T) | ((tv5 - tv6) <= T) |
               ((tv6 - tv7) <= T) | ((tv7 - rm)  <= T);

    float ce0, ce1, ce2, ce3, ce4, ce5, ce6, ce7;
    int   o0, o1, o2, o3, o4, o5, o6, o7;

    if (__builtin_expect(!tie, 1)) {
        // fast path: no representable score tie possible
        ce0 = 1.0f;
        ce1 = __expf(tv1 - tv0); ce2 = __expf(tv2 - tv0);
        ce3 = __expf(tv3 - tv0); ce4 = __expf(tv4 - tv0);
        ce5 = __expf(tv5 - tv0); ce6 = __expf(tv6 - tv0);
        ce7 = __expf(tv7 - tv0);
        o0 = ti0; o1 = ti1; o2 = ti2; o3 = ti3;
        o4 = ti4; o5 = ti5; o6 = ti6; o7 = ti7;
    } else {
        // exact path (rare, exec-masked): re-read the row from global and
        // redo depth-10 selection + correctly-rounded-exp tie semantics.
        const float* rowp = logits + (size_t)row * NEXP;
        float sv0 = -INFINITY, sv1 = -INFINITY, sv2 = -INFINITY, sv3 = -INFINITY;
        float sv4 = -INFINITY, sv5 = -INFINITY, sv6 = -INFINITY, sv7 = -INFINITY;
        float sv8 = -INFINITY, sv9 = -INFINITY;
        int   si0 = 0, si1 = 0, si2 = 0, si3 = 0, si4 = 0;
        int   si5 = 0, si6 = 0, si7 = 0, si8 = 0, si9 = 0;

#define SLOW_STAGE(TV, TI)                                \
    {                                                     \
        bool gt = (x > TV);                               \
        float nv = gt ? x  : TV;                          \
        float cv = gt ? TV : x;                           \
        int   ni = gt ? xi : TI;                          \
        int   ci = gt ? TI : xi;                          \
        TV = nv; x = cv; TI = ni; xi = ci;                \
    }

        #pragma unroll 1
        for (int e = 0; e < NEXP; ++e) {
            float x = rowp[e]; int xi = e;
            SLOW_STAGE(sv0, si0)
            SLOW_STAGE(sv1, si1)
            SLOW_STAGE(sv2, si2)
            SLOW_STAGE(sv3, si3)
            SLOW_STAGE(sv4, si4)
            SLOW_STAGE(sv5, si5)
            SLOW_STAGE(sv6, si6)
            SLOW_STAGE(sv7, si7)
            SLOW_STAGE(sv8, si8)
            SLOW_STAGE(sv9, si9)
        }

        double m = (double)sv0;
        float s0 = (float)exp((double)sv0 - m);
        float s1 = (float)exp((double)sv1 - m);
        float s2 = (float)exp((double)sv2 - m);
        float s3 = (float)exp((double)sv3 - m);
        float s4 = (float)exp((double)sv4 - m);
        float s5 = (float)exp((double)sv5 - m);
        float s6 = (float)exp((double)sv6 - m);
        float s7 = (float)exp((double)sv7 - m);
        float s8 = (float)exp((double)sv8 - m);
        float s9 = (float)exp((double)sv9 - m);

#define TIESWAP(CA, IA, CB, IB)                           \
    {                                                     \
        bool sw = (CA == CB) && (IA > IB);                \
        int tt = IA;                                      \
        IA = sw ? IB : IA;                                \
        IB = sw ? tt : IB;                                \
    }
#define TIEPASS                                           \
    TIESWAP(s0, si0, s1, si1)                             \
    TIESWAP(s1, si1, s2, si2)                             \
    TIESWAP(s2, si2, s3, si3)                             \
    TIESWAP(s3, si3, s4, si4)                             \
    TIESWAP(s4, si4, s5, si5)                             \
    TIESWAP(s5, si5, s6, si6)                             \
    TIESWAP(s6, si6, s7, si7)                             \
    TIESWAP(s7, si7, s8, si8)                             \
    TIESWAP(s8, si8, s9, si9)

        TIEPASS
        TIEPASS
        TIEPASS
        TIEPASS

        ce0 = s0; ce1 = s1; ce2 = s2; ce3 = s3;
        ce4 = s4; ce5 = s5; ce6 = s6; ce7 = s7;
        o0 = si0; o1 = si1; o2 = si2; o3 = si3;
        o4 = si4; o5 = si5; o6 = si6; o7 = si7;
    }

    float s = ((ce0 + ce1) + (ce2 + ce3)) + ((ce4 + ce5) + (ce6 + ce7));
    float r = 1.0f / s;

    float4 w0 = make_float4(ce0 * r, ce1 * r, ce2 * r, ce3 * r);
    float4 w1 = make_float4(ce4 * r, ce5 * r, ce6 * r, ce7 * r);
    float4 i0 = make_float4((float)o0, (float)o1, (float)o2, (float)o3);
    float4 i1 = make_float4((float)o4, (float)o5, (float)o6, (float)o7);

    float4* __restrict__ wp = (float4*)(w_out + (size_t)row * TOPK);
    wp[0] = w0; wp[1] = w1;
    float4* __restrict__ ip = (float4*)(id_out + (size_t)row * TOPK);
    ip[0] = i0; ip[1] = i1;
}

extern "C" void kernel_launch(void* const* d_in, const int* in_sizes, int n_in,
                              void* d_out, int out_size, void* d_ws, size_t ws_size,
                              hipStream_t stream) {
    const float* logits = (const float*)d_in[0];
    int nrows = in_sizes[0] / NEXP;

    float* out    = (float*)d_out;
    float* w_out  = out;
    float* id_out = out + (size_t)nrows * TOPK;
    float* l_out  = out + (size_t)nrows * 2 * TOPK;

    int threads = 256;
    int blocks = (nrows + RPB - 1) / RPB;
    topk_router_kernel<<<blocks, threads, 0, stream>>>(logits, w_out, id_out, l_out, nrows);
}